// Round 1
// baseline (3589.491 us; speedup 1.0000x reference)
//
#include <hip/hip_runtime.h>
#include <hip/hip_fp16.h>

#define T_SEQ 2048
#define NBATCH 64
#define DIM 128      // SEQ_LEN
#define HID 128      // HIDDEN
#define G4 512       // 4*HID

__device__ __forceinline__ float sigmoidf_(float x) {
    return 1.0f / (1.0f + __expf(-x));
}
__device__ __forceinline__ float tanhf_(float x) {
    float e = __expf(-2.0f * fabsf(x));       // in (0,1], no overflow
    float t = __fdividef(1.0f - e, 1.0f + e);
    return copysignf(t, x);
}

// ---------------- Phase 1: pre[t][b][g] = x[b][t][:] @ W_ih[:,g] + bias[g] ----------------
// grid.x = tc (local timestep), block = 512 threads (one per gate column g)
__global__ __launch_bounds__(512, 2) void pre_gemm(
    const float* __restrict__ x,      // [B][T][DIM]
    const float* __restrict__ Wih,    // [DIM][G4]
    const float* __restrict__ bias,   // [G4]
    float* __restrict__ pre,          // [tc][B][G4]
    int t0)
{
    __shared__ __align__(16) float xs[NBATCH][DIM];
    const int lt = blockIdx.x;
    const int t  = t0 + lt;
    const int g  = threadIdx.x;

    // stage x rows for all 64 batches at this t: 8192 floats = 2048 float4
    for (int i = g; i < NBATCH * DIM / 4; i += 512) {
        int row  = i >> 5;      // 32 float4 per row
        int col4 = i & 31;
        float4 v = *reinterpret_cast<const float4*>(
            x + (size_t)row * (T_SEQ * DIM) + (size_t)t * DIM + col4 * 4);
        *reinterpret_cast<float4*>(&xs[row][col4 * 4]) = v;
    }

    // W_ih column g into registers
    float w[DIM];
    #pragma unroll
    for (int k = 0; k < DIM; ++k) w[k] = Wih[(size_t)k * G4 + g];

    __syncthreads();
    const float bg = bias[g];

    for (int bb = 0; bb < NBATCH; ++bb) {
        float a0 = bg, a1 = 0.f, a2 = 0.f, a3 = 0.f;
        #pragma unroll
        for (int kk = 0; kk < DIM / 4; ++kk) {
            float4 hv = *reinterpret_cast<const float4*>(&xs[bb][kk * 4]);
            a0 = fmaf(hv.x, w[kk * 4 + 0], a0);
            a1 = fmaf(hv.y, w[kk * 4 + 1], a1);
            a2 = fmaf(hv.z, w[kk * 4 + 2], a2);
            a3 = fmaf(hv.w, w[kk * 4 + 3], a3);
        }
        pre[((size_t)lt * NBATCH + bb) * G4 + g] = (a0 + a1) + (a2 + a3);
    }
}

// ---------------- Phase 2: sequential LSTM scan over a chunk of tc timesteps ----------------
// grid.x = batch b (64 blocks), block = 512 threads (one per gate column g)
// state layout (floats): h[64*128] | c[64*128] | facc0[64*128] | facc1[64*128]
__global__ __launch_bounds__(512, 2) void lstm_scan(
    const float* __restrict__ pre,    // [tc][B][G4]
    const float* __restrict__ Whh,    // [HID][G4]
    const float* __restrict__ h0,
    const float* __restrict__ c0,
    const float* __restrict__ fcw,    // [2][T*HID]
    const float* __restrict__ fcb,    // [2]
    float* __restrict__ state,
    float* __restrict__ out,          // [B][2]
    int t0, int tc)
{
    __shared__ __align__(16) float h_sh[HID];
    __shared__ float gate_sh[G4];
    __shared__ float red[2][HID];

    const int b = blockIdx.x;
    const int g = threadIdx.x;
    const int gtype = g >> 7;         // 0:i 1:f 2:g 3:o

    float* st_h  = state;
    float* st_c  = state + NBATCH * HID;
    float* st_f0 = state + 2 * NBATCH * HID;
    float* st_f1 = state + 3 * NBATCH * HID;

    // W_hh column g into registers
    float w[HID];
    #pragma unroll
    for (int k = 0; k < HID; ++k) w[k] = Whh[(size_t)k * G4 + g];

    float c = 0.f, facc0 = 0.f, facc1 = 0.f;
    if (g < HID) {
        if (t0 == 0) {
            h_sh[g] = h0[b * HID + g];
            c       = c0[b * HID + g];
        } else {
            h_sh[g] = st_h[b * HID + g];
            c       = st_c[b * HID + g];
            facc0   = st_f0[b * HID + g];
            facc1   = st_f1[b * HID + g];
        }
    }
    __syncthreads();

    // software-pipelined loads
    float p = pre[((size_t)0 * NBATCH + b) * G4 + g];
    float fw0 = 0.f, fw1 = 0.f;
    if (g < HID) {
        fw0 = fcw[(size_t)t0 * HID + g];
        fw1 = fcw[(size_t)T_SEQ * HID + (size_t)t0 * HID + g];
    }

    for (int lt = 0; lt < tc; ++lt) {
        float p_n = 0.f, fw0_n = 0.f, fw1_n = 0.f;
        if (lt + 1 < tc) {
            p_n = pre[((size_t)(lt + 1) * NBATCH + b) * G4 + g];
            if (g < HID) {
                size_t gt = (size_t)(t0 + lt + 1) * HID + g;
                fw0_n = fcw[gt];
                fw1_n = fcw[(size_t)T_SEQ * HID + gt];
            }
        }

        float a0 = p, a1 = 0.f, a2 = 0.f, a3 = 0.f;
        #pragma unroll
        for (int kk = 0; kk < HID / 4; ++kk) {
            float4 hv = *reinterpret_cast<const float4*>(&h_sh[kk * 4]);
            a0 = fmaf(hv.x, w[kk * 4 + 0], a0);
            a1 = fmaf(hv.y, w[kk * 4 + 1], a1);
            a2 = fmaf(hv.z, w[kk * 4 + 2], a2);
            a3 = fmaf(hv.w, w[kk * 4 + 3], a3);
        }
        float acc = (a0 + a1) + (a2 + a3);
        float act = (gtype == 2) ? tanhf_(acc) : sigmoidf_(acc);
        gate_sh[g] = act;
        __syncthreads();

        if (g < HID) {
            float gi = gate_sh[g];
            float gf = gate_sh[g + 128];
            float gg = gate_sh[g + 256];
            float go = gate_sh[g + 384];
            c = fmaf(gf, c, gi * gg);
            float hn = go * tanhf_(c);
            h_sh[g] = hn;
            facc0 = fmaf(hn, fw0, facc0);
            facc1 = fmaf(hn, fw1, facc1);
        }
        __syncthreads();

        p = p_n; fw0 = fw0_n; fw1 = fw1_n;
    }

    if (t0 + tc >= T_SEQ) {
        // final: reduce fc accumulators and emit out[b][0:2]
        if (g < HID) { red[0][g] = facc0; red[1][g] = facc1; }
        __syncthreads();
        if (g == 0) {
            float s0 = 0.f, s1 = 0.f;
            for (int k = 0; k < HID; ++k) { s0 += red[0][k]; s1 += red[1][k]; }
            out[b * 2 + 0] = s0 + fcb[0];
            out[b * 2 + 1] = s1 + fcb[1];
        }
    } else {
        if (g < HID) {
            st_h[b * HID + g]  = h_sh[g];
            st_c[b * HID + g]  = c;
            st_f0[b * HID + g] = facc0;
            st_f1[b * HID + g] = facc1;
        }
    }
}

extern "C" void kernel_launch(void* const* d_in, const int* in_sizes, int n_in,
                              void* d_out, int out_size, void* d_ws, size_t ws_size,
                              hipStream_t stream) {
    const float* x    = (const float*)d_in[0];
    const float* h0   = (const float*)d_in[1];
    const float* c0   = (const float*)d_in[2];
    const float* Wih  = (const float*)d_in[3];
    const float* Whh  = (const float*)d_in[4];
    const float* bias = (const float*)d_in[5];
    const float* fcw  = (const float*)d_in[6];
    const float* fcb  = (const float*)d_in[7];
    float* out = (float*)d_out;

    // ws layout: state header (4 * 64*128 floats = 128 KB), then pre chunk buffer
    float* state = (float*)d_ws;
    const size_t state_floats = (size_t)4 * NBATCH * HID;
    float* pre = state + state_floats;

    const size_t per_t_bytes = (size_t)NBATCH * G4 * sizeof(float); // 128 KB per timestep
    size_t avail = (ws_size > state_floats * sizeof(float))
                       ? ws_size - state_floats * sizeof(float) : 0;
    int Tc = (int)(avail / per_t_bytes);
    if (Tc < 1) Tc = 1;            // degenerate fallback
    if (Tc > T_SEQ) Tc = T_SEQ;

    for (int t0 = 0; t0 < T_SEQ; t0 += Tc) {
        int tc = (t0 + Tc <= T_SEQ) ? Tc : (T_SEQ - t0);
        pre_gemm<<<tc, 512, 0, stream>>>(x, Wih, bias, pre, t0);
        lstm_scan<<<64, 512, 0, stream>>>(pre, Whh, h0, c0, fcw, fcb,
                                          state, out, t0, tc);
    }
}

// Round 2
// 2390.352 us; speedup vs baseline: 1.5017x; 1.5017x over previous
//
#include <hip/hip_runtime.h>

#define T_SEQ 2048
#define NBATCH 64
#define DIM 128      // SEQ_LEN
#define HID 128      // HIDDEN
#define G4 512       // 4*HID

typedef _Float16 h2v __attribute__((ext_vector_type(2)));

__device__ __forceinline__ unsigned pack2(float lo, float hi) {
    h2v v; v.x = (_Float16)lo; v.y = (_Float16)hi;
    return __builtin_bit_cast(unsigned, v);
}
__device__ __forceinline__ float dot2(unsigned a, unsigned b, float c) {
#if __has_builtin(__builtin_amdgcn_fdot2)
    return __builtin_amdgcn_fdot2(__builtin_bit_cast(h2v, a),
                                  __builtin_bit_cast(h2v, b), c, false);
#else
    h2v av = __builtin_bit_cast(h2v, a), bv = __builtin_bit_cast(h2v, b);
    c = fmaf((float)av.x, (float)bv.x, c);
    return fmaf((float)av.y, (float)bv.y, c);
#endif
}
__device__ __forceinline__ unsigned bcast(unsigned v, int lane) {
    return (unsigned)__builtin_amdgcn_readlane((int)v, lane);
}
__device__ __forceinline__ float sigmoidf_(float x) {
    return 1.0f / (1.0f + __expf(-x));
}
__device__ __forceinline__ float tanhf_(float x) {
    float e = __expf(-2.0f * fabsf(x));
    float t = __fdividef(1.0f - e, 1.0f + e);
    return copysignf(t, x);
}

// ---------------- Phase 1: pre16[lt][b][g] = f16( x[b][t][:] @ W_ih[:,g] + bias[g] ) -----
// grid.x = tc (local timestep), block = 512 threads (one per gate column g)
__global__ __launch_bounds__(512, 2) void pre_gemm16(
    const float* __restrict__ x,      // [B][T][DIM]
    const float* __restrict__ Wih,    // [DIM][G4]
    const float* __restrict__ bias,   // [G4]
    _Float16* __restrict__ pre,       // [tc][B][G4]
    int t0)
{
    __shared__ unsigned xs[NBATCH][64];   // packed f16 pairs, word w = x[.][2w],x[.][2w+1]
    const int lt = blockIdx.x;
    const int t  = t0 + lt;
    const int g  = threadIdx.x;
    const int lane = threadIdx.x & 63;

    // stage x rows (64 batches at this t) as packed f16: 4096 words
    for (int i = g; i < NBATCH * 64; i += 512) {
        int row  = i >> 6;
        int word = i & 63;
        float2 v = *reinterpret_cast<const float2*>(
            x + (size_t)row * (T_SEQ * DIM) + (size_t)t * DIM + word * 2);
        xs[row][word] = pack2(v.x, v.y);
    }

    // W_ih column g, packed f16 pairs, in registers
    unsigned wpk[64];
    #pragma unroll
    for (int i = 0; i < 64; ++i)
        wpk[i] = pack2(Wih[(size_t)(2 * i) * G4 + g],
                       Wih[(size_t)(2 * i + 1) * G4 + g]);

    __syncthreads();
    const float bg = bias[g];

    for (int b = 0; b < NBATCH; ++b) {
        unsigned xw = xs[b][lane];         // lane l holds word l of row b
        float a0 = bg, a1 = 0.f, a2 = 0.f, a3 = 0.f;
        #pragma unroll
        for (int k = 0; k < 64; k += 4) {
            a0 = dot2(bcast(xw, k + 0), wpk[k + 0], a0);
            a1 = dot2(bcast(xw, k + 1), wpk[k + 1], a1);
            a2 = dot2(bcast(xw, k + 2), wpk[k + 2], a2);
            a3 = dot2(bcast(xw, k + 3), wpk[k + 3], a3);
        }
        pre[((size_t)lt * NBATCH + b) * G4 + g] = (_Float16)((a0 + a1) + (a2 + a3));
    }
}

// ---------------- Phase 2: sequential LSTM scan over a chunk of tc timesteps ----------------
// grid.x = batch b (64 blocks), block = 512 threads (one per gate column g)
// state layout (floats): h[64*128] | c[64*128] | facc0[64*128] | facc1[64*128]
__global__ __launch_bounds__(512, 2) void lstm_scan(
    const _Float16* __restrict__ pre, // [tc][B][G4]
    const float* __restrict__ Whh,    // [HID][G4]
    const float* __restrict__ h0,
    const float* __restrict__ c0,
    const float* __restrict__ fcw,    // [2][T*HID]
    const float* __restrict__ fcb,    // [2]
    float* __restrict__ state,
    float* __restrict__ out,          // [B][2]
    int t0, int tc)
{
    __shared__ unsigned h_words[64];      // h as packed f16 pairs
    __shared__ float gate_sh[G4];
    __shared__ float red[2][HID];

    const int b = blockIdx.x;
    const int g = threadIdx.x;
    const int lane = threadIdx.x & 63;
    const int gtype = g >> 7;             // 0:i 1:f 2:g 3:o (wave-uniform)

    float* st_h  = state;
    float* st_c  = state + NBATCH * HID;
    float* st_f0 = state + 2 * NBATCH * HID;
    float* st_f1 = state + 3 * NBATCH * HID;

    // W_hh column g, packed f16 pairs, in registers
    unsigned wpk[64];
    #pragma unroll
    for (int i = 0; i < 64; ++i)
        wpk[i] = pack2(Whh[(size_t)(2 * i) * G4 + g],
                       Whh[(size_t)(2 * i + 1) * G4 + g]);

    float c = 0.f, facc0 = 0.f, facc1 = 0.f, h_cur = 0.f;
    if (g < HID) {
        if (t0 == 0) {
            h_cur = h0[b * HID + g];
            c     = c0[b * HID + g];
        } else {
            h_cur = st_h[b * HID + g];
            c     = st_c[b * HID + g];
            facc0 = st_f0[b * HID + g];
            facc1 = st_f1[b * HID + g];
        }
        reinterpret_cast<_Float16*>(h_words)[g] = (_Float16)h_cur;
    }
    __syncthreads();

    // software-pipelined loads
    float p = (float)pre[((size_t)0 * NBATCH + b) * G4 + g];
    float fw0 = 0.f, fw1 = 0.f;
    if (g < HID) {
        fw0 = fcw[(size_t)t0 * HID + g];
        fw1 = fcw[(size_t)T_SEQ * HID + (size_t)t0 * HID + g];
    }

    for (int lt = 0; lt < tc; ++lt) {
        unsigned hw = h_words[lane];      // lane l holds packed pair (h[2l], h[2l+1])

        float p_n = 0.f, fw0_n = 0.f, fw1_n = 0.f;
        if (lt + 1 < tc) {
            p_n = (float)pre[((size_t)(lt + 1) * NBATCH + b) * G4 + g];
            if (g < HID) {
                size_t gt = (size_t)(t0 + lt + 1) * HID + g;
                fw0_n = fcw[gt];
                fw1_n = fcw[(size_t)T_SEQ * HID + gt];
            }
        }

        float a0 = p, a1 = 0.f, a2 = 0.f, a3 = 0.f;
        #pragma unroll
        for (int k = 0; k < 64; k += 4) {
            a0 = dot2(bcast(hw, k + 0), wpk[k + 0], a0);
            a1 = dot2(bcast(hw, k + 1), wpk[k + 1], a1);
            a2 = dot2(bcast(hw, k + 2), wpk[k + 2], a2);
            a3 = dot2(bcast(hw, k + 3), wpk[k + 3], a3);
        }
        float acc = (a0 + a1) + (a2 + a3);
        float act = (gtype == 2) ? tanhf_(acc) : sigmoidf_(acc);
        gate_sh[g] = act;
        __syncthreads();

        if (g < HID) {
            float gi = gate_sh[g];
            float gf = gate_sh[g + 128];
            float gg = gate_sh[g + 256];
            float go = gate_sh[g + 384];
            c = fmaf(gf, c, gi * gg);
            float hn = go * tanhf_(c);
            h_cur = hn;
            reinterpret_cast<_Float16*>(h_words)[g] = (_Float16)hn;
            facc0 = fmaf(hn, fw0, facc0);
            facc1 = fmaf(hn, fw1, facc1);
        }
        __syncthreads();

        p = p_n; fw0 = fw0_n; fw1 = fw1_n;
    }

    if (t0 + tc >= T_SEQ) {
        if (g < HID) { red[0][g] = facc0; red[1][g] = facc1; }
        __syncthreads();
        if (g == 0) {
            float s0 = 0.f, s1 = 0.f;
            for (int k = 0; k < HID; ++k) { s0 += red[0][k]; s1 += red[1][k]; }
            out[b * 2 + 0] = s0 + fcb[0];
            out[b * 2 + 1] = s1 + fcb[1];
        }
    } else {
        if (g < HID) {
            st_h[b * HID + g]  = h_cur;
            st_c[b * HID + g]  = c;
            st_f0[b * HID + g] = facc0;
            st_f1[b * HID + g] = facc1;
        }
    }
}

extern "C" void kernel_launch(void* const* d_in, const int* in_sizes, int n_in,
                              void* d_out, int out_size, void* d_ws, size_t ws_size,
                              hipStream_t stream) {
    const float* x    = (const float*)d_in[0];
    const float* h0   = (const float*)d_in[1];
    const float* c0   = (const float*)d_in[2];
    const float* Wih  = (const float*)d_in[3];
    const float* Whh  = (const float*)d_in[4];
    const float* bias = (const float*)d_in[5];
    const float* fcw  = (const float*)d_in[6];
    const float* fcb  = (const float*)d_in[7];
    float* out = (float*)d_out;

    // ws layout: state header (4 * 64*128 floats = 128 KB), then f16 pre chunk buffer
    float* state = (float*)d_ws;
    const size_t state_floats = (size_t)4 * NBATCH * HID;
    _Float16* pre = (_Float16*)(state + state_floats);

    const size_t per_t_bytes = (size_t)NBATCH * G4 * sizeof(_Float16); // 64 KB per timestep
    size_t avail = (ws_size > state_floats * sizeof(float))
                       ? ws_size - state_floats * sizeof(float) : 0;
    int Tc = (int)(avail / per_t_bytes);
    if (Tc < 1) Tc = 1;
    if (Tc > T_SEQ) Tc = T_SEQ;

    for (int t0 = 0; t0 < T_SEQ; t0 += Tc) {
        int tc = (t0 + Tc <= T_SEQ) ? Tc : (T_SEQ - t0);
        pre_gemm16<<<tc, 512, 0, stream>>>(x, Wih, bias, pre, t0);
        lstm_scan<<<64, 512, 0, stream>>>(pre, Whh, h0, c0, fcw, fcb,
                                          state, out, t0, tc);
    }
}